// Round 8
// baseline (232.714 us; speedup 1.0000x reference)
//
#include <hip/hip_runtime.h>
#include <hip/hip_bf16.h>

#define EPSV  1e-5f
// C^-0.5 * log2(e): softmax then uses exp2 directly
#define QSC   0.0901684400555650f

typedef __attribute__((ext_vector_type(8))) __bf16 bfrag;   // MFMA A/B operand
typedef __attribute__((ext_vector_type(4))) float  f32x4;
typedef __attribute__((ext_vector_type(8))) short  s16x8;
typedef __attribute__((ext_vector_type(4))) short  s16x4;

static __device__ __forceinline__ short f2b(float f) {
    __hip_bfloat16 h = __float2bfloat16(f);
    return __builtin_bit_cast(short, h);
}

// async global->LDS, 16B per lane; LDS dest = wave-uniform base + lane*16
#define GLDS16(SRC, DST) __builtin_amdgcn_global_load_lds( \
    (__attribute__((address_space(1))) void*)(SRC),        \
    (__attribute__((address_space(3))) void*)(DST), 16, 0, 0)

// ---------------------------------------------------------------------------
// K1: GroupNorm partial sums (blocks 0..255)  +  weight transpose to bf16
//     (blocks 256..1279) fused into one launch.
// ---------------------------------------------------------------------------
__global__ __launch_bounds__(256) void gn_part_prep(const float* __restrict__ x,
                                                    float* __restrict__ part,
                                                    const float* __restrict__ wq,
                                                    const float* __restrict__ wk,
                                                    const float* __restrict__ wv,
                                                    const float* __restrict__ wo,
                                                    short* __restrict__ wt) {
    if (blockIdx.x >= 256) {
        const int bb = blockIdx.x - 256;
        const int z = bb >> 8;
        const int n = bb & 255;
        const int k = threadIdx.x;
        const float* w = (z == 0) ? wq : (z == 1) ? wk : (z == 2) ? wv : wo;
        wt[(z * 256 + n) * 256 + k] = f2b(w[k * 256 + n]);
        return;
    }
    const int b = blockIdx.x >> 3, ch = blockIdx.x & 7;
    const int t = threadIdx.x;
    const int c4 = t & 63;
    const int rr = t >> 6;
    float s1 = 0.f, s2 = 0.f;
    for (int i = 0; i < 32; ++i) {
        const int pos = ch * 128 + rr + (i << 2);
        const f32x4 v = *reinterpret_cast<const f32x4*>(x + (((b << 10) + pos) << 8) + (c4 << 2));
        s1 += v[0] + v[1] + v[2] + v[3];
        s2 += v[0]*v[0] + v[1]*v[1] + v[2]*v[2] + v[3]*v[3];
    }
    __shared__ float ls1[256], ls2[256];
    ls1[t] = s1; ls2[t] = s2;
    __syncthreads();
    if (t < 32) {
        float a1 = 0.f, a2 = 0.f;
        for (int r2 = 0; r2 < 4; ++r2)
            for (int e = 0; e < 2; ++e) {
                const int idx = r2 * 64 + t * 2 + e;
                a1 += ls1[idx]; a2 += ls2[idx];
            }
        part[((b * 8 + ch) * 32 + t) * 2 + 0] = a1;
        part[((b * 8 + ch) * 32 + t) * 2 + 1] = a2;
    }
}

// ---------------------------------------------------------------------------
// K2: fused GN-finalize + GN-normalize + QKV projection.
// ---------------------------------------------------------------------------
__global__ __launch_bounds__(256) void qkv_gemm(const float* __restrict__ x,
                                                const float* __restrict__ part,
                                                const float* __restrict__ gns,
                                                const float* __restrict__ gnb,
                                                const short* __restrict__ wt,
                                                const float* __restrict__ bq,
                                                const float* __restrict__ bk,
                                                const float* __restrict__ bv,
                                                short* __restrict__ qo,
                                                short* __restrict__ ko,
                                                short* __restrict__ vtg) {
    __shared__ short At[64][264];
    __shared__ float gmean[32], grstd[32];
    __shared__ float sA[256], sB[256];

    const int t  = threadIdx.x;
    const int m0 = blockIdx.x * 64;
    const int b  = m0 >> 10;
    const int lane = t & 63, w = t >> 6;
    const int lr = lane & 15, lh = lane >> 4;

    if (t < 32) {
        float s1 = 0.f, s2 = 0.f;
        for (int ch = 0; ch < 8; ++ch) {
            s1 += part[((b * 8 + ch) * 32 + t) * 2 + 0];
            s2 += part[((b * 8 + ch) * 32 + t) * 2 + 1];
        }
        const float mean = s1 * (1.f / 8192.f);
        const float var  = s2 * (1.f / 8192.f) - mean * mean;
        gmean[t] = mean;
        grstd[t] = rsqrtf(var + EPSV);
    }
    __syncthreads();
    {
        const float a = grstd[t >> 3] * gns[t];
        sA[t] = a;
        sB[t] = gnb[t] - gmean[t >> 3] * a;
    }
    __syncthreads();

    {
        const int r = t >> 2, q4 = t & 3;
        const float* xrow = x + (m0 + r) * 256;
        for (int i = 0; i < 16; ++i) {
            const int c0 = (q4 + 4 * i) * 4;
            const f32x4 v  = *reinterpret_cast<const f32x4*>(xrow + c0);
            const f32x4 aa = *reinterpret_cast<const f32x4*>(&sA[c0]);
            const f32x4 bb = *reinterpret_cast<const f32x4*>(&sB[c0]);
            s16x4 o;
            for (int j = 0; j < 4; ++j) o[j] = f2b(v[j] * aa[j] + bb[j]);
            *reinterpret_cast<s16x4*>(&At[r][c0]) = o;
        }
    }
    __syncthreads();

    for (int z = 0; z < 3; ++z) {
        f32x4 acc[4][4];
        for (int mi = 0; mi < 4; ++mi)
            for (int ni = 0; ni < 4; ++ni) acc[mi][ni] = (f32x4){0.f, 0.f, 0.f, 0.f};
        const short* wz = wt + z * 65536 + (w * 64 + lr) * 256 + lh * 8;
#pragma unroll
        for (int kt = 0; kt < 8; ++kt) {
            bfrag bf[4];
#pragma unroll
            for (int ni = 0; ni < 4; ++ni)
                bf[ni] = *reinterpret_cast<const bfrag*>(wz + ni * 4096 + kt * 32);
            bfrag af[4];
#pragma unroll
            for (int mi = 0; mi < 4; ++mi)
                af[mi] = *reinterpret_cast<const bfrag*>(&At[mi * 16 + lr][kt * 32 + lh * 8]);
#pragma unroll
            for (int ni = 0; ni < 4; ++ni)
#pragma unroll
                for (int mi = 0; mi < 4; ++mi)
                    acc[mi][ni] = __builtin_amdgcn_mfma_f32_16x16x32_bf16(af[mi], bf[ni], acc[mi][ni], 0, 0, 0);
        }
        if (z == 2) {
            for (int ni = 0; ni < 4; ++ni) {
                const int col = w * 64 + ni * 16 + lr;
                const float bb = bv[col];
                for (int mi = 0; mi < 4; ++mi) {
                    const int pos = (m0 & 1023) + mi * 16 + lh * 4;
                    s16x4 ov;
                    for (int j = 0; j < 4; ++j) ov[j] = f2b(acc[mi][ni][j] + bb);
                    *reinterpret_cast<s16x4*>(&vtg[(((b << 8) + col) << 10) + pos]) = ov;
                }
            }
        } else {
            short* outp = (z == 0) ? qo : ko;
            const float* bias = (z == 0) ? bq : bk;
            const float s = (z == 0) ? QSC : 1.0f;
            for (int ni = 0; ni < 4; ++ni) {
                const int col = w * 64 + ni * 16 + lr;
                const float bsc = bias[col] * s;
                for (int mi = 0; mi < 4; ++mi) {
                    const int row = m0 + mi * 16 + lh * 4;
                    for (int j = 0; j < 4; ++j)
                        outp[(row + j) * 256 + col] = f2b(acc[mi][ni][j] * s + bsc);
                }
            }
        }
    }
}

// ---------------------------------------------------------------------------
// K3: flash attention, FAT WAVES: 4 waves (256 thr), 32 q-rows per wave,
// QBLK=128, grid = 256 (XCD-swizzled) = 1 block/CU.
// Each K/V fragment read feeds TWO MFMAs -> per-CU LDS read traffic halves.
// PV pairing: pa{qb}0 = keys 0..31 pairs with vb0 (keys 0..31);
//             pa{qb}1 = keys 32..63 pairs with vb1 (keys 32..63).
// ---------------------------------------------------------------------------
__global__ __launch_bounds__(256) void attn(const short* __restrict__ qq,
                                            const short* __restrict__ kk,
                                            const short* __restrict__ vt,
                                            short* __restrict__ ao) {
    __shared__ __align__(1024) short Kt[2][64 * 256];   // 2 x 32 KB
    __shared__ __align__(1024) short Vt[2][256 * 64];   // 2 x 32 KB
    __shared__ __align__(1024) short Pl[4][32 * 64];    // 16 KB (per-wave, 32q x 64k)

    int bid = blockIdx.x;
    bid = ((bid & 7) << 5) | (bid >> 3);   // XCD swizzle: 4 batches/XCD in L2
    const int b = bid >> 3, qt = bid & 7;
    const int t = threadIdx.x;
    const int w = t >> 6, lane = t & 63;
    const int lr = lane & 15, lh = lane >> 4;
    const int qr0 = qt * 128 + w * 32;     // wave owns q-rows qr0..qr0+31
    const int sw = lr & 7;

    // Q fragments for both q-halves (q pre-scaled by C^-0.5*log2e)
    bfrag qf[2][8];
#pragma unroll
    for (int qb2 = 0; qb2 < 2; ++qb2) {
        const short* qp = qq + (((b << 10) + qr0 + qb2 * 16 + lr) << 8) + lh * 8;
#pragma unroll
        for (int ks = 0; ks < 8; ++ks)
            qf[qb2][ks] = *reinterpret_cast<const bfrag*>(qp + ks * 32);
    }

    const short* kbase = kk + ((long)b << 18);
    const short* vbase = vt + ((long)b << 18);
    short* plw = Pl[w];

    // staging share per wave: K rows w*16..+15 (8 x 2 rows), V rows w*64..+63
    auto stageK = [&](int kt_, int buf) {
#pragma unroll
        for (int t2 = 0; t2 < 8; ++t2) {
            const int rbase = w * 16 + t2 * 2;
            const int r  = rbase + (lane >> 5);
            const int gs = (lane & 31) ^ (r & 7);
            GLDS16(kbase + ((kt_ * 64 + r) << 8) + (gs << 3), &Kt[buf][rbase << 8]);
        }
    };
    auto stageV = [&](int kt_, int buf) {
#pragma unroll
        for (int t2 = 0; t2 < 8; ++t2) {
            const int rbase = w * 64 + t2 * 8;
            const int r  = rbase + (lane >> 3);
            const int gs = (lane & 7) ^ (r & 7);
            GLDS16(vbase + (r << 10) + kt_ * 64 + (gs << 3), &Vt[buf][rbase << 6]);
        }
    };

    f32x4 o0[16], o1[16];
#pragma unroll
    for (int ci = 0; ci < 16; ++ci) {
        o0[ci] = (f32x4){0.f, 0.f, 0.f, 0.f};
        o1[ci] = (f32x4){0.f, 0.f, 0.f, 0.f};
    }
    float m0v = -3e38f, m1v = -3e38f;
    float ls0 = 0.f, ls1 = 0.f;    // lazy per-lane partial sums

    stageK(0, 0); stageV(0, 0);    // 16 loads in flight per thread

    for (int kt = 0; kt < 16; ++kt) {
        const int cur = kt & 1;
        __asm__ volatile("s_barrier" ::: "memory");
        if (kt < 15) {
            stageK(kt + 1, cur ^ 1);
            stageV(kt + 1, cur ^ 1);
            __asm__ volatile("s_waitcnt vmcnt(16)" ::: "memory");
        } else {
            __asm__ volatile("s_waitcnt vmcnt(0)" ::: "memory");
        }
        __asm__ volatile("s_barrier" ::: "memory");

        // ---- S^T = K . Q : s{qb}[ni] = S[key=ni*16+lh*4+r][q=qb*16+lr]
        f32x4 s0[4], s1[4];
#pragma unroll
        for (int ni = 0; ni < 4; ++ni) {
            s0[ni] = (f32x4){0.f, 0.f, 0.f, 0.f};
            s1[ni] = (f32x4){0.f, 0.f, 0.f, 0.f};
        }
        __builtin_amdgcn_s_setprio(1);
#pragma unroll
        for (int ks = 0; ks < 8; ++ks) {
#pragma unroll
            for (int ni = 0; ni < 4; ++ni) {
                const int row = ni * 16 + lr;
                const bfrag kf = *reinterpret_cast<const bfrag*>(
                    &Kt[cur][(row << 8) + ((((ks << 2) + lh) ^ sw) << 3)]);
                s0[ni] = __builtin_amdgcn_mfma_f32_16x16x32_bf16(kf, qf[0][ks], s0[ni], 0, 0, 0);
                s1[ni] = __builtin_amdgcn_mfma_f32_16x16x32_bf16(kf, qf[1][ks], s1[ni], 0, 0, 0);
            }
        }
        __builtin_amdgcn_s_setprio(0);

        // ---- online softmax (base-2), per-lane rows q=lr (qb0) and 16+lr (qb1)
        float rm0 = fmaxf(fmaxf(s0[0][0], s0[0][1]), fmaxf(s0[0][2], s0[0][3]));
        float rm1 = fmaxf(fmaxf(s1[0][0], s1[0][1]), fmaxf(s1[0][2], s1[0][3]));
#pragma unroll
        for (int ni = 1; ni < 4; ++ni) {
            rm0 = fmaxf(rm0, fmaxf(fmaxf(s0[ni][0], s0[ni][1]), fmaxf(s0[ni][2], s0[ni][3])));
            rm1 = fmaxf(rm1, fmaxf(fmaxf(s1[ni][0], s1[ni][1]), fmaxf(s1[ni][2], s1[ni][3])));
        }
        rm0 = fmaxf(rm0, __shfl_xor(rm0, 16)); rm0 = fmaxf(rm0, __shfl_xor(rm0, 32));
        rm1 = fmaxf(rm1, __shfl_xor(rm1, 16)); rm1 = fmaxf(rm1, __shfl_xor(rm1, 32));

        const bool grow = __any(rm0 > m0v || rm1 > m1v);
        float p0[4][4], p1[4][4];
        float rs0 = 0.f, rs1 = 0.f;
        if (grow) {
            const float mn0 = fmaxf(m0v, rm0), mn1 = fmaxf(m1v, rm1);
            const float sc0 = exp2f(m0v - mn0), sc1 = exp2f(m1v - mn1);
            m0v = mn0; m1v = mn1;
#pragma unroll
            for (int ni = 0; ni < 4; ++ni)
#pragma unroll
                for (int r2 = 0; r2 < 4; ++r2) {
                    p0[ni][r2] = exp2f(s0[ni][r2] - mn0); rs0 += p0[ni][r2];
                    p1[ni][r2] = exp2f(s1[ni][r2] - mn1); rs1 += p1[ni][r2];
                }
            ls0 = ls0 * sc0 + rs0;
            ls1 = ls1 * sc1 + rs1;
            float sb0[4], sb1[4];
#pragma unroll
            for (int j = 0; j < 4; ++j) {
                sb0[j] = __shfl(sc0, lh * 4 + j);
                sb1[j] = __shfl(sc1, lh * 4 + j);
            }
#pragma unroll
            for (int ci = 0; ci < 16; ++ci)
#pragma unroll
                for (int j = 0; j < 4; ++j) {
                    o0[ci][j] *= sb0[j];
                    o1[ci][j] *= sb1[j];
                }
        } else {
#pragma unroll
            for (int ni = 0; ni < 4; ++ni)
#pragma unroll
                for (int r2 = 0; r2 < 4; ++r2) {
                    p0[ni][r2] = exp2f(s0[ni][r2] - m0v); rs0 += p0[ni][r2];
                    p1[ni][r2] = exp2f(s1[ni][r2] - m1v); rs1 += p1[ni][r2];
                }
            ls0 += rs0;
            ls1 += rs1;
        }

        // ---- stage P (both q-halves), row q = qb*16+lr, swizzled b64
#pragma unroll
        for (int ni = 0; ni < 4; ++ni) {
            s16x4 pw0, pw1;
#pragma unroll
            for (int r2 = 0; r2 < 4; ++r2) { pw0[r2] = f2b(p0[ni][r2]); pw1[r2] = f2b(p1[ni][r2]); }
            const int gc = (ni << 1) + (lh >> 1);
            const int ad = (lr << 6) + ((gc ^ sw) << 3) + ((lh & 1) << 2);
            *reinterpret_cast<s16x4*>(&plw[ad]) = pw0;
            *reinterpret_cast<s16x4*>(&plw[1024 + ad]) = pw1;   // rows 16..31
        }
        // pa{qb}0: keys 0..31 (granules lh);  pa{qb}1: keys 32..63 (granules lh+4)
        const bfrag pa00 = *reinterpret_cast<const bfrag*>(&plw[(lr << 6) + ((lh ^ sw) << 3)]);
        const bfrag pa01 = *reinterpret_cast<const bfrag*>(&plw[(lr << 6) + (((4 + lh) ^ sw) << 3)]);
        const bfrag pa10 = *reinterpret_cast<const bfrag*>(&plw[1024 + (lr << 6) + ((lh ^ sw) << 3)]);
        const bfrag pa11 = *reinterpret_cast<const bfrag*>(&plw[1024 + (lr << 6) + (((4 + lh) ^ sw) << 3)]);

        // ---- O += P . V  (key halves matched: pa*0@vb0, pa*1@vb1)
        __builtin_amdgcn_s_setprio(1);
#pragma unroll
        for (int ci = 0; ci < 16; ++ci) {
            const int row = (ci << 4) + lr;
            const bfrag vb0 = *reinterpret_cast<const bfrag*>(
                &Vt[cur][(row << 6) + ((lh ^ sw) << 3)]);
            const bfrag vb1 = *reinterpret_cast<const bfrag*>(
                &Vt[cur][(row << 6) + (((4 + lh) ^ sw) << 3)]);
            o0[ci] = __builtin_amdgcn_mfma_f32_16x16x32_bf16(pa00, vb0, o0[ci], 0, 0, 0);
            o1[ci] = __builtin_amdgcn_mfma_f32_16x16x32_bf16(pa10, vb0, o1[ci], 0, 0, 0);
            o0[ci] = __builtin_amdgcn_mfma_f32_16x16x32_bf16(pa01, vb1, o0[ci], 0, 0, 0);
            o1[ci] = __builtin_amdgcn_mfma_f32_16x16x32_bf16(pa11, vb1, o1[ci], 0, 0, 0);
        }
        __builtin_amdgcn_s_setprio(0);
    }

    // lazy lsum reduction
    ls0 += __shfl_xor(ls0, 16); ls0 += __shfl_xor(ls0, 32);
    ls1 += __shfl_xor(ls1, 16); ls1 += __shfl_xor(ls1, 32);

    float iv0[4], iv1[4];
#pragma unroll
    for (int j = 0; j < 4; ++j) {
        iv0[j] = 1.0f / __shfl(ls0, lh * 4 + j);
        iv1[j] = 1.0f / __shfl(ls1, lh * 4 + j);
    }
#pragma unroll
    for (int j = 0; j < 4; ++j) {
        const int row0 = (b << 10) + qr0 + lh * 4 + j;
        const int row1 = row0 + 16;
        for (int ci = 0; ci < 16; ++ci) {
            ao[(row0 << 8) + (ci << 4) + lr] = f2b(o0[ci][j] * iv0[j]);
            ao[(row1 << 8) + (ci << 4) + lr] = f2b(o1[ci][j] * iv1[j]);
        }
    }
}

// ---------------------------------------------------------------------------
// K4: output projection + bias + residual.  B direct from global (L2-hot).
// ---------------------------------------------------------------------------
__global__ __launch_bounds__(256) void oproj(const short* __restrict__ ao,
                                             const short* __restrict__ wto,
                                             const float* __restrict__ bo,
                                             const float* __restrict__ x,
                                             float* __restrict__ out) {
    __shared__ short At[64][264];

    const int t  = threadIdx.x;
    const int m0 = blockIdx.x * 64;
    const int lane = t & 63, w = t >> 6;
    const int lr = lane & 15, lh = lane >> 4;

    {
        const int r = t >> 2, q4 = t & 3;
        const short* ap = ao + (m0 + r) * 256;
        for (int i = 0; i < 8; ++i) {
            const int c0 = (q4 + 4 * i) * 8;
            *reinterpret_cast<s16x8*>(&At[r][c0]) = *reinterpret_cast<const s16x8*>(ap + c0);
        }
    }
    __syncthreads();

    f32x4 acc[4][4];
    for (int mi = 0; mi < 4; ++mi)
        for (int ni = 0; ni < 4; ++ni) acc[mi][ni] = (f32x4){0.f, 0.f, 0.f, 0.f};

    const short* wz = wto + (w * 64 + lr) * 256 + lh * 8;
#pragma unroll
    for (int kt = 0; kt < 8; ++kt) {
        bfrag bf[4];
#pragma unroll
        for (int ni = 0; ni < 4; ++ni)
            bf[ni] = *reinterpret_cast<const bfrag*>(wz + ni * 4096 + kt * 32);
        bfrag af[4];
#pragma unroll
        for (int mi = 0; mi < 4; ++mi)
            af[mi] = *reinterpret_cast<const bfrag*>(&At[mi * 16 + lr][kt * 32 + lh * 8]);
#pragma unroll
        for (int ni = 0; ni < 4; ++ni)
#pragma unroll
            for (int mi = 0; mi < 4; ++mi)
                acc[mi][ni] = __builtin_amdgcn_mfma_f32_16x16x32_bf16(af[mi], bf[ni], acc[mi][ni], 0, 0, 0);
    }

    for (int ni = 0; ni < 4; ++ni) {
        const int col = w * 64 + ni * 16 + lr;
        const float bb = bo[col];
        for (int mi = 0; mi < 4; ++mi) {
            const int row = m0 + mi * 16 + lh * 4;
            for (int j = 0; j < 4; ++j) {
                const int idx = (row + j) * 256 + col;
                out[idx] = acc[mi][ni][j] + bb + x[idx];
            }
        }
    }
}

// ---------------------------------------------------------------------------
extern "C" void kernel_launch(void* const* d_in, const int* in_sizes, int n_in,
                              void* d_out, int out_size, void* d_ws, size_t ws_size,
                              hipStream_t stream) {
    const float* x   = (const float*)d_in[0];
    const float* gns = (const float*)d_in[1];
    const float* gnb = (const float*)d_in[2];
    const float* Wq  = (const float*)d_in[3];
    const float* bq  = (const float*)d_in[4];
    const float* Wk  = (const float*)d_in[5];
    const float* bk  = (const float*)d_in[6];
    const float* Wv  = (const float*)d_in[7];
    const float* bv  = (const float*)d_in[8];
    const float* Wo  = (const float*)d_in[9];
    const float* bo  = (const float*)d_in[10];
    float* out = (float*)d_out;

    char* ws = (char*)d_ws;
    short* wt   = (short*)(ws);
    float* part = (float*)(ws + 524288);
    const size_t MB16 = 16777216;
    short* qb  = (short*)(ws + (1 << 20));
    short* kb  = (short*)(ws + (1 << 20) + MB16);
    short* vtb = (short*)(ws + (1 << 20) + 2 * MB16);
    short* aob = (short*)(ws + (1 << 20) + 3 * MB16);

    hipLaunchKernelGGL(gn_part_prep, dim3(1280), dim3(256), 0, stream,
                       x, part, Wq, Wk, Wv, Wo, wt);
    hipLaunchKernelGGL(qkv_gemm, dim3(512), dim3(256), 0, stream,
                       x, part, gns, gnb, wt, bq, bk, bv, qb, kb, vtb);
    hipLaunchKernelGGL(attn, dim3(256), dim3(256), 0, stream, qb, kb, vtb, aob);
    hipLaunchKernelGGL(oproj, dim3(512), dim3(256), 0, stream,
                       aob, wt + 3 * 65536, bo, x, out);
}

// Round 9
// 166.287 us; speedup vs baseline: 1.3995x; 1.3995x over previous
//
#include <hip/hip_runtime.h>
#include <hip/hip_bf16.h>

#define EPSV  1e-5f
// C^-0.5 * log2(e): softmax then uses exp2 directly
#define QSC   0.0901684400555650f

typedef __attribute__((ext_vector_type(8)))  __bf16 bfrag;   // MFMA A/B operand
typedef __attribute__((ext_vector_type(4)))  float  f32x4;
typedef __attribute__((ext_vector_type(16))) float  f32x16;  // 32x32 MFMA C/D
typedef __attribute__((ext_vector_type(8)))  short  s16x8;
typedef __attribute__((ext_vector_type(4)))  short  s16x4;

static __device__ __forceinline__ short f2b(float f) {
    __hip_bfloat16 h = __float2bfloat16(f);
    return __builtin_bit_cast(short, h);
}

// async global->LDS, 16B per lane; LDS dest = wave-uniform base + lane*16
#define GLDS16(SRC, DST) __builtin_amdgcn_global_load_lds( \
    (__attribute__((address_space(1))) void*)(SRC),        \
    (__attribute__((address_space(3))) void*)(DST), 16, 0, 0)

// ---------------------------------------------------------------------------
// K1: GroupNorm partial sums (blocks 0..255)  +  weight transpose to bf16
//     (blocks 256..1279) fused into one launch.
// ---------------------------------------------------------------------------
__global__ __launch_bounds__(256) void gn_part_prep(const float* __restrict__ x,
                                                    float* __restrict__ part,
                                                    const float* __restrict__ wq,
                                                    const float* __restrict__ wk,
                                                    const float* __restrict__ wv,
                                                    const float* __restrict__ wo,
                                                    short* __restrict__ wt) {
    if (blockIdx.x >= 256) {
        const int bb = blockIdx.x - 256;
        const int z = bb >> 8;
        const int n = bb & 255;
        const int k = threadIdx.x;
        const float* w = (z == 0) ? wq : (z == 1) ? wk : (z == 2) ? wv : wo;
        wt[(z * 256 + n) * 256 + k] = f2b(w[k * 256 + n]);
        return;
    }
    const int b = blockIdx.x >> 3, ch = blockIdx.x & 7;
    const int t = threadIdx.x;
    const int c4 = t & 63;
    const int rr = t >> 6;
    float s1 = 0.f, s2 = 0.f;
    for (int i = 0; i < 32; ++i) {
        const int pos = ch * 128 + rr + (i << 2);
        const f32x4 v = *reinterpret_cast<const f32x4*>(x + (((b << 10) + pos) << 8) + (c4 << 2));
        s1 += v[0] + v[1] + v[2] + v[3];
        s2 += v[0]*v[0] + v[1]*v[1] + v[2]*v[2] + v[3]*v[3];
    }
    __shared__ float ls1[256], ls2[256];
    ls1[t] = s1; ls2[t] = s2;
    __syncthreads();
    if (t < 32) {
        float a1 = 0.f, a2 = 0.f;
        for (int r2 = 0; r2 < 4; ++r2)
            for (int e = 0; e < 2; ++e) {
                const int idx = r2 * 64 + t * 2 + e;
                a1 += ls1[idx]; a2 += ls2[idx];
            }
        part[((b * 8 + ch) * 32 + t) * 2 + 0] = a1;
        part[((b * 8 + ch) * 32 + t) * 2 + 1] = a2;
    }
}

// ---------------------------------------------------------------------------
// K2: fused GN-finalize + GN-normalize + QKV projection.
// ---------------------------------------------------------------------------
__global__ __launch_bounds__(256) void qkv_gemm(const float* __restrict__ x,
                                                const float* __restrict__ part,
                                                const float* __restrict__ gns,
                                                const float* __restrict__ gnb,
                                                const short* __restrict__ wt,
                                                const float* __restrict__ bq,
                                                const float* __restrict__ bk,
                                                const float* __restrict__ bv,
                                                short* __restrict__ qo,
                                                short* __restrict__ ko,
                                                short* __restrict__ vtg) {
    __shared__ short At[64][264];
    __shared__ float gmean[32], grstd[32];
    __shared__ float sA[256], sB[256];

    const int t  = threadIdx.x;
    const int m0 = blockIdx.x * 64;
    const int b  = m0 >> 10;
    const int lane = t & 63, w = t >> 6;
    const int lr = lane & 15, lh = lane >> 4;

    if (t < 32) {
        float s1 = 0.f, s2 = 0.f;
        for (int ch = 0; ch < 8; ++ch) {
            s1 += part[((b * 8 + ch) * 32 + t) * 2 + 0];
            s2 += part[((b * 8 + ch) * 32 + t) * 2 + 1];
        }
        const float mean = s1 * (1.f / 8192.f);
        const float var  = s2 * (1.f / 8192.f) - mean * mean;
        gmean[t] = mean;
        grstd[t] = rsqrtf(var + EPSV);
    }
    __syncthreads();
    {
        const float a = grstd[t >> 3] * gns[t];
        sA[t] = a;
        sB[t] = gnb[t] - gmean[t >> 3] * a;
    }
    __syncthreads();

    {
        const int r = t >> 2, q4 = t & 3;
        const float* xrow = x + (m0 + r) * 256;
        for (int i = 0; i < 16; ++i) {
            const int c0 = (q4 + 4 * i) * 4;
            const f32x4 v  = *reinterpret_cast<const f32x4*>(xrow + c0);
            const f32x4 aa = *reinterpret_cast<const f32x4*>(&sA[c0]);
            const f32x4 bb = *reinterpret_cast<const f32x4*>(&sB[c0]);
            s16x4 o;
            for (int j = 0; j < 4; ++j) o[j] = f2b(v[j] * aa[j] + bb[j]);
            *reinterpret_cast<s16x4*>(&At[r][c0]) = o;
        }
    }
    __syncthreads();

    for (int z = 0; z < 3; ++z) {
        f32x4 acc[4][4];
        for (int mi = 0; mi < 4; ++mi)
            for (int ni = 0; ni < 4; ++ni) acc[mi][ni] = (f32x4){0.f, 0.f, 0.f, 0.f};
        const short* wz = wt + z * 65536 + (w * 64 + lr) * 256 + lh * 8;
#pragma unroll
        for (int kt = 0; kt < 8; ++kt) {
            bfrag bf[4];
#pragma unroll
            for (int ni = 0; ni < 4; ++ni)
                bf[ni] = *reinterpret_cast<const bfrag*>(wz + ni * 4096 + kt * 32);
            bfrag af[4];
#pragma unroll
            for (int mi = 0; mi < 4; ++mi)
                af[mi] = *reinterpret_cast<const bfrag*>(&At[mi * 16 + lr][kt * 32 + lh * 8]);
#pragma unroll
            for (int ni = 0; ni < 4; ++ni)
#pragma unroll
                for (int mi = 0; mi < 4; ++mi)
                    acc[mi][ni] = __builtin_amdgcn_mfma_f32_16x16x32_bf16(af[mi], bf[ni], acc[mi][ni], 0, 0, 0);
        }
        if (z == 2) {
            for (int ni = 0; ni < 4; ++ni) {
                const int col = w * 64 + ni * 16 + lr;
                const float bb = bv[col];
                for (int mi = 0; mi < 4; ++mi) {
                    const int pos = (m0 & 1023) + mi * 16 + lh * 4;
                    s16x4 ov;
                    for (int j = 0; j < 4; ++j) ov[j] = f2b(acc[mi][ni][j] + bb);
                    *reinterpret_cast<s16x4*>(&vtg[(((b << 8) + col) << 10) + pos]) = ov;
                }
            }
        } else {
            short* outp = (z == 0) ? qo : ko;
            const float* bias = (z == 0) ? bq : bk;
            const float s = (z == 0) ? QSC : 1.0f;
            for (int ni = 0; ni < 4; ++ni) {
                const int col = w * 64 + ni * 16 + lr;
                const float bsc = bias[col] * s;
                for (int mi = 0; mi < 4; ++mi) {
                    const int row = m0 + mi * 16 + lh * 4;
                    for (int j = 0; j < 4; ++j)
                        outp[(row + j) * 256 + col] = f2b(acc[mi][ni][j] * s + bsc);
                }
            }
        }
    }
}

// ---------------------------------------------------------------------------
// K3: flash attention with 32x32x16 MFMAs.  4 waves (256 thr), 32 q-rows
// per wave, QBLK=128, grid = 256 (XCD-swizzled) = 1 block/CU = 1 wave/SIMD.
// One b128 LDS fragment read now feeds 32768 FLOP (2x the 16x16 path) ->
// per-CU LDS read traffic halves.  VGPR budget opened to 512 via
// __launch_bounds__(256,1) (free at 1 wave/SIMD) to avoid round-8's spill.
// Lane layout (m101): C/D col=lane&31 (=q), row=(reg&3)+8*(reg>>2)+4*(lane>>5).
// A-frag: lane holds A[m=lane&31][k=(lane>>5)*8+j]; B-frag: B[k][n=lane&31].
// ---------------------------------------------------------------------------
__global__ __launch_bounds__(256, 1) void attn(const short* __restrict__ qq,
                                               const short* __restrict__ kk,
                                               const short* __restrict__ vt,
                                               short* __restrict__ ao) {
    __shared__ __align__(1024) short Kt[2][64 * 256];   // 2 x 32 KB
    __shared__ __align__(1024) short Vt[2][256 * 64];   // 2 x 32 KB
    __shared__ __align__(1024) short Pl[4][32 * 64];    // 16 KB (per-wave)

    int bid = blockIdx.x;
    bid = ((bid & 7) << 5) | (bid >> 3);   // XCD swizzle: 4 batches/XCD in L2
    const int b = bid >> 3, qt = bid & 7;
    const int t = threadIdx.x;
    const int w = t >> 6, lane = t & 63;
    const int q = lane & 31;               // this lane's q-row (within wave)
    const int h = lane >> 5;               // k-half selector
    const int qs = q & 7;                  // swizzle key (row ≡ q mod 8)
    const int qr0 = qt * 128 + w * 32;     // wave owns q-rows qr0..qr0+31

    // Q fragments as MFMA B-operand: qf[ks] -> Q[q][k=ks*16 + h*8 + j]
    bfrag qf[16];
    {
        const short* qp = qq + (((b << 10) + qr0 + q) << 8) + (h << 3);
#pragma unroll
        for (int ks = 0; ks < 16; ++ks)
            qf[ks] = *reinterpret_cast<const bfrag*>(qp + (ks << 4));
    }

    const short* kbase = kk + ((long)b << 18);
    const short* vbase = vt + ((long)b << 18);
    short* plw = Pl[w];

    // staging share per wave: K rows w*16..+15, V rows w*64..+63
    auto stageK = [&](int kt_, int buf) {
#pragma unroll
        for (int t2 = 0; t2 < 8; ++t2) {
            const int rbase = w * 16 + t2 * 2;
            const int r  = rbase + (lane >> 5);
            const int gs = (lane & 31) ^ (r & 7);
            GLDS16(kbase + ((kt_ * 64 + r) << 8) + (gs << 3), &Kt[buf][rbase << 8]);
        }
    };
    auto stageV = [&](int kt_, int buf) {
#pragma unroll
        for (int t2 = 0; t2 < 8; ++t2) {
            const int rbase = w * 64 + t2 * 8;
            const int r  = rbase + (lane >> 3);
            const int gs = (lane & 7) ^ (r & 7);
            GLDS16(vbase + (r << 10) + kt_ * 64 + (gs << 3), &Vt[buf][rbase << 6]);
        }
    };

    f32x16 o[8];
#pragma unroll
    for (int dt = 0; dt < 8; ++dt)
#pragma unroll
        for (int j = 0; j < 16; ++j) o[dt][j] = 0.f;
    float mv = -3e38f, ls = 0.f;           // per-lane (q-row) softmax state

    stageK(0, 0); stageV(0, 0);            // 16 loads in flight per thread

    for (int kt = 0; kt < 16; ++kt) {
        const int cur = kt & 1;
        __asm__ volatile("s_barrier" ::: "memory");
        if (kt < 15) {
            stageK(kt + 1, cur ^ 1);
            stageV(kt + 1, cur ^ 1);
            __asm__ volatile("s_waitcnt vmcnt(16)" ::: "memory");
        } else {
            __asm__ volatile("s_waitcnt vmcnt(0)" ::: "memory");
        }
        __asm__ volatile("s_barrier" ::: "memory");

        // ---- S^T = K . Q : sacc[kt2] = S[key=kt2*32+rowmap][q]
        f32x16 sacc[2];
#pragma unroll
        for (int kt2 = 0; kt2 < 2; ++kt2)
#pragma unroll
            for (int j = 0; j < 16; ++j) sacc[kt2][j] = 0.f;
        __builtin_amdgcn_s_setprio(1);
#pragma unroll
        for (int ks = 0; ks < 16; ++ks) {
            const int G = (ks << 1) + h;
#pragma unroll
            for (int kt2 = 0; kt2 < 2; ++kt2) {
                const int arow = kt2 * 32 + q;
                const bfrag ka = *reinterpret_cast<const bfrag*>(
                    &Kt[cur][(arow << 8) + ((G ^ qs) << 3)]);
                sacc[kt2] = __builtin_amdgcn_mfma_f32_32x32x16_bf16(ka, qf[ks], sacc[kt2], 0, 0, 0);
            }
        }
        __builtin_amdgcn_s_setprio(0);

        // ---- online softmax (base-2): lane holds 32 of 64 keys for its q;
        //      the complementary 32 live in lane^32.
        float rm = sacc[0][0];
#pragma unroll
        for (int j = 1; j < 16; ++j) rm = fmaxf(rm, sacc[0][j]);
#pragma unroll
        for (int j = 0; j < 16; ++j) rm = fmaxf(rm, sacc[1][j]);
        rm = fmaxf(rm, __shfl_xor(rm, 32));

        const bool grow = __any(rm > mv);
        const float mn = grow ? fmaxf(mv, rm) : mv;
        float rs = 0.f;
        // P = exp2(S - mn), staged to per-wave LDS (swizzled), rs accumulated.
        // reg r of tile kt2 -> key = kt2*32 + (r&3) + 8*(r>>2) + 4*h
#pragma unroll
        for (int kt2 = 0; kt2 < 2; ++kt2)
#pragma unroll
            for (int grp = 0; grp < 4; ++grp) {
                s16x4 pw;
#pragma unroll
                for (int j = 0; j < 4; ++j) {
                    const float v = exp2f(sacc[kt2][grp * 4 + j] - mn);
                    rs += v;
                    pw[j] = f2b(v);
                }
                const int g = (kt2 << 2) + grp;          // 16B granule of key block
                const int ad = (q << 6) + ((g ^ qs) << 3) + (h << 2);
                *reinterpret_cast<s16x4*>(&plw[ad]) = pw;
            }

        if (grow) {
            const float sc = exp2f(mv - mn);
            mv = mn;
            ls = ls * sc + rs;
#pragma unroll
            for (int dt = 0; dt < 8; ++dt) o[dt] *= sc;
        } else {
            ls += rs;
        }

        // ---- O^T += V^T . P : o[dt] covers d = dt*32+rowmap, all 32 q
        __builtin_amdgcn_s_setprio(1);
#pragma unroll
        for (int kf = 0; kf < 4; ++kf) {
            const int gp = (kf << 1) + h;
            const bfrag pb = *reinterpret_cast<const bfrag*>(
                &plw[(q << 6) + ((gp ^ qs) << 3)]);
#pragma unroll
            for (int dt = 0; dt < 8; ++dt) {
                const int vrow = dt * 32 + q;
                const bfrag va = *reinterpret_cast<const bfrag*>(
                    &Vt[cur][(vrow << 6) + ((gp ^ qs) << 3)]);
                o[dt] = __builtin_amdgcn_mfma_f32_32x32x16_bf16(va, pb, o[dt], 0, 0, 0);
            }
        }
        __builtin_amdgcn_s_setprio(0);
    }

    // final: lane pair (l, l^32) holds disjoint key-halves' partial sums
    ls += __shfl_xor(ls, 32);
    const float inv = 1.0f / ls;

    // store: d = dt*32 + grp*8 + 4h + j, row = b*1024 + qr0 + q
    {
        short* aop = ao + ((((b << 10) + qr0 + q)) << 8) + (h << 2);
#pragma unroll
        for (int dt = 0; dt < 8; ++dt)
#pragma unroll
            for (int grp = 0; grp < 4; ++grp) {
                s16x4 ov;
#pragma unroll
                for (int j = 0; j < 4; ++j) ov[j] = f2b(o[dt][grp * 4 + j] * inv);
                *reinterpret_cast<s16x4*>(&aop[dt * 32 + grp * 8]) = ov;
            }
    }
}

// ---------------------------------------------------------------------------
// K4: output projection + bias + residual.  B direct from global (L2-hot).
// ---------------------------------------------------------------------------
__global__ __launch_bounds__(256) void oproj(const short* __restrict__ ao,
                                             const short* __restrict__ wto,
                                             const float* __restrict__ bo,
                                             const float* __restrict__ x,
                                             float* __restrict__ out) {
    __shared__ short At[64][264];

    const int t  = threadIdx.x;
    const int m0 = blockIdx.x * 64;
    const int lane = t & 63, w = t >> 6;
    const int lr = lane & 15, lh = lane >> 4;

    {
        const int r = t >> 2, q4 = t & 3;
        const short* ap = ao + (m0 + r) * 256;
        for (int i = 0; i < 8; ++i) {
            const int c0 = (q4 + 4 * i) * 8;
            *reinterpret_cast<s16x8*>(&At[r][c0]) = *reinterpret_cast<const s16x8*>(ap + c0);
        }
    }
    __syncthreads();

    f32x4 acc[4][4];
    for (int mi = 0; mi < 4; ++mi)
        for (int ni = 0; ni < 4; ++ni) acc[mi][ni] = (f32x4){0.f, 0.f, 0.f, 0.f};

    const short* wz = wto + (w * 64 + lr) * 256 + lh * 8;
#pragma unroll
    for (int kt = 0; kt < 8; ++kt) {
        bfrag bf[4];
#pragma unroll
        for (int ni = 0; ni < 4; ++ni)
            bf[ni] = *reinterpret_cast<const bfrag*>(wz + ni * 4096 + kt * 32);
        bfrag af[4];
#pragma unroll
        for (int mi = 0; mi < 4; ++mi)
            af[mi] = *reinterpret_cast<const bfrag*>(&At[mi * 16 + lr][kt * 32 + lh * 8]);
#pragma unroll
        for (int ni = 0; ni < 4; ++ni)
#pragma unroll
            for (int mi = 0; mi < 4; ++mi)
                acc[mi][ni] = __builtin_amdgcn_mfma_f32_16x16x32_bf16(af[mi], bf[ni], acc[mi][ni], 0, 0, 0);
    }

    for (int ni = 0; ni < 4; ++ni) {
        const int col = w * 64 + ni * 16 + lr;
        const float bb = bo[col];
        for (int mi = 0; mi < 4; ++mi) {
            const int row = m0 + mi * 16 + lh * 4;
            for (int j = 0; j < 4; ++j) {
                const int idx = (row + j) * 256 + col;
                out[idx] = acc[mi][ni][j] + bb + x[idx];
            }
        }
    }
}

// ---------------------------------------------------------------------------
extern "C" void kernel_launch(void* const* d_in, const int* in_sizes, int n_in,
                              void* d_out, int out_size, void* d_ws, size_t ws_size,
                              hipStream_t stream) {
    const float* x   = (const float*)d_in[0];
    const float* gns = (const float*)d_in[1];
    const float* gnb = (const float*)d_in[2];
    const float* Wq  = (const float*)d_in[3];
    const float* bq  = (const float*)d_in[4];
    const float* Wk  = (const float*)d_in[5];
    const float* bk  = (const float*)d_in[6];
    const float* Wv  = (const float*)d_in[7];
    const float* bv  = (const float*)d_in[8];
    const float* Wo  = (const float*)d_in[9];
    const float* bo  = (const float*)d_in[10];
    float* out = (float*)d_out;

    char* ws = (char*)d_ws;
    short* wt   = (short*)(ws);
    float* part = (float*)(ws + 524288);
    const size_t MB16 = 16777216;
    short* qb  = (short*)(ws + (1 << 20));
    short* kb  = (short*)(ws + (1 << 20) + MB16);
    short* vtb = (short*)(ws + (1 << 20) + 2 * MB16);
    short* aob = (short*)(ws + (1 << 20) + 3 * MB16);

    hipLaunchKernelGGL(gn_part_prep, dim3(1280), dim3(256), 0, stream,
                       x, part, Wq, Wk, Wv, Wo, wt);
    hipLaunchKernelGGL(qkv_gemm, dim3(512), dim3(256), 0, stream,
                       x, part, gns, gnb, wt, bq, bk, bv, qb, kb, vtb);
    hipLaunchKernelGGL(attn, dim3(256), dim3(256), 0, stream, qb, kb, vtb, aob);
    hipLaunchKernelGGL(oproj, dim3(512), dim3(256), 0, stream,
                       aob, wt + 3 * 65536, bo, x, out);
}